// Round 1
// baseline (517.847 us; speedup 1.0000x reference)
//
#include <hip/hip_runtime.h>
#include <math.h>

// Problem constants (HierarchicalAttention: WML=64, B=64, S=40, D=512)
#define BB   64
#define SS   40
#define WMLC 64
#define DD   512
#define NN   2560           // S*WML
#define NBLK 20             // chunks (blocks) per batch for the main pass
#define WPB  4              // waves per block
#define NWAVES (NBLK*WPB)   // 80 waves per batch
#define RPW (NN/NWAVES)     // 32 rows per wave
#define L2E 1.4426950408889634f

__device__ __forceinline__ float wave_reduce_sum(float v) {
    // butterfly across all 64 lanes; every lane ends with the total
    #pragma unroll
    for (int off = 32; off > 0; off >>= 1) v += __shfl_xor(v, off, 64);
    return v;
}

// ---------------------------------------------------------------------------
// K1: q_w = source @ W_word^T ; q_s = source @ W_sent^T     [B, D] each
// grid (2, B): x=0 -> W_word/qw, x=1 -> W_sent/qs. 256 thr; thread t does
// rows d=t and d=t+256 of W (row-major (D,D): q[b,d] = sum_k src[b,k]*W[d,k]).
// ---------------------------------------------------------------------------
__global__ __launch_bounds__(256) void k_proj(const float* __restrict__ src,
                                              const float* __restrict__ Ww,
                                              const float* __restrict__ Ws,
                                              float* __restrict__ qw,
                                              float* __restrict__ qs) {
    __shared__ float xs[DD];
    const int b = blockIdx.y;
    const int t = threadIdx.x;
    const float* W = blockIdx.x ? Ws : Ww;
    float* q = blockIdx.x ? qs : qw;
    ((float2*)xs)[t] = ((const float2*)(src + b * DD))[t];
    __syncthreads();
    const float* r0 = W + (size_t)t * DD;
    const float* r1 = W + (size_t)(t + 256) * DD;
    float acc0 = 0.f, acc1 = 0.f;
    for (int k = 0; k < DD; k += 4) {
        float4 x  = *(const float4*)(xs + k);
        float4 w0 = *(const float4*)(r0 + k);
        float4 w1 = *(const float4*)(r1 + k);
        acc0 += x.x * w0.x + x.y * w0.y + x.z * w0.z + x.w * w0.w;
        acc1 += x.x * w1.x + x.y * w1.y + x.z * w1.z + x.w * w1.w;
    }
    q[b * DD + t] = acc0;
    q[b * DD + t + 256] = acc1;
}

// ---------------------------------------------------------------------------
// K2: sstat[b,s] = dot(q_s[b,:], sent_bank[s,b,:]) * static_attn[b,s]
// grid (B), 4 waves, each wave does 10 sentences.
// ---------------------------------------------------------------------------
__global__ __launch_bounds__(256) void k_sstat(const float* __restrict__ qs,
                                               const float* __restrict__ sb,
                                               const float* __restrict__ sa,
                                               float* __restrict__ sstat) {
    const int b = blockIdx.x;
    const int t = threadIdx.x, wave = t >> 6, lane = t & 63;
    const int d0 = lane * 4, d1 = 256 + lane * 4;
    const float4 q0 = *(const float4*)(qs + b * DD + d0);
    const float4 q1 = *(const float4*)(qs + b * DD + d1);
    for (int j = 0; j < SS / WPB; ++j) {
        const int s = wave * (SS / WPB) + j;
        const float* row = sb + ((size_t)s * BB + b) * DD;
        float4 a0 = *(const float4*)(row + d0);
        float4 a1 = *(const float4*)(row + d1);
        float p = a0.x * q0.x + a0.y * q0.y + a0.z * q0.z + a0.w * q0.w
                + a1.x * q1.x + a1.y * q1.y + a1.z * q1.z + a1.w * q1.w;
        p = wave_reduce_sum(p);
        if (lane == 0) sstat[b * SS + s] = p * sa[b * SS + s];
    }
}

// ---------------------------------------------------------------------------
// K3 (main, HBM-bound): single streaming pass over the VALID rows of
// word_bank. One wave owns rows n = gw + 80k (k<32), all within batch b.
// Per row: 512B/lane*... 2 float4 loads, dot vs q_w, online-softmax
// accumulate of c. Masked rows (w >= word_lengths) are skipped ENTIRELY
// (no load) — ~49% traffic saved. Raw scores go straight into the d_out
// align region (finalized in-place by K5). Block writes one (m,l,c[512])
// partial.
// ---------------------------------------------------------------------------
__global__ __launch_bounds__(256) void k_main(const float* __restrict__ wb,
                                              const float* __restrict__ qw,
                                              const float* __restrict__ sstat,
                                              const int* __restrict__ wl,
                                              float* __restrict__ scores,
                                              float* __restrict__ part_c,
                                              float* __restrict__ part_ml) {
    const int b = blockIdx.y;
    const int chunk = blockIdx.x;
    const int t = threadIdx.x, wave = t >> 6, lane = t & 63;
    const int gw = chunk * WPB + wave;               // 0..79
    const int d0 = lane * 4, d1 = 256 + lane * 4;
    const float4 q0 = *(const float4*)(qw + b * DD + d0);
    const float4 q1 = *(const float4*)(qw + b * DD + d1);

    float m = -INFINITY, l = 0.f;
    float4 c0 = {0.f, 0.f, 0.f, 0.f}, c1 = {0.f, 0.f, 0.f, 0.f};

    for (int k = 0; k < RPW; ++k) {
        const int n = gw + k * NWAVES;
        const int s = n >> 6, w = n & 63;
        if (w >= wl[b * SS + s]) continue;           // wave-uniform skip
        const float* row = wb + (size_t)(((w * BB + b) * SS + s)) * DD;
        float4 a0 = *(const float4*)(row + d0);
        float4 a1 = *(const float4*)(row + d1);
        float p = a0.x * q0.x + a0.y * q0.y + a0.z * q0.z + a0.w * q0.w
                + a1.x * q1.x + a1.y * q1.y + a1.z * q1.z + a1.w * q1.w;
        p = wave_reduce_sum(p);
        const float a = p * sstat[b * SS + s];
        if (lane == 0) scores[b * NN + n] = a;
        if (a > m) {
            const float sc = (m == -INFINITY) ? 0.f : exp2f((m - a) * L2E);
            l *= sc;
            c0.x *= sc; c0.y *= sc; c0.z *= sc; c0.w *= sc;
            c1.x *= sc; c1.y *= sc; c1.z *= sc; c1.w *= sc;
            m = a;
        }
        const float e = exp2f((a - m) * L2E);
        l += e;
        c0.x += e * a0.x; c0.y += e * a0.y; c0.z += e * a0.z; c0.w += e * a0.w;
        c1.x += e * a1.x; c1.y += e * a1.y; c1.z += e * a1.z; c1.w += e * a1.w;
    }

    // intra-block combine of the 4 wave partials
    __shared__ float s_m[WPB], s_l[WPB];
    __shared__ float s_c[WPB][DD];
    *(float4*)(&s_c[wave][d0]) = c0;
    *(float4*)(&s_c[wave][d1]) = c1;
    if (lane == 0) { s_m[wave] = m; s_l[wave] = l; }
    __syncthreads();
    const float mb = fmaxf(fmaxf(s_m[0], s_m[1]), fmaxf(s_m[2], s_m[3]));
    float lb = 0.f, cA = 0.f, cB = 0.f;
    #pragma unroll
    for (int wv = 0; wv < WPB; ++wv) {
        const float mi = s_m[wv];
        const float sc = (mi == -INFINITY) ? 0.f : exp2f((mi - mb) * L2E);
        lb += s_l[wv] * sc;
        cA += s_c[wv][t] * sc;
        cB += s_c[wv][t + 256] * sc;
    }
    const int pidx = b * NBLK + chunk;
    part_c[(size_t)pidx * DD + t] = cA;
    part_c[(size_t)pidx * DD + t + 256] = cB;
    if (t == 0) { part_ml[pidx * 2] = mb; part_ml[pidx * 2 + 1] = lb; }
}

// ---------------------------------------------------------------------------
// K4: per-batch reduction of the NBLK partials -> c_final[b,:], m_g, 1/Z
// ---------------------------------------------------------------------------
__global__ __launch_bounds__(256) void k_reduce(const float* __restrict__ part_c,
                                                const float* __restrict__ part_ml,
                                                float* __restrict__ c_final,
                                                float* __restrict__ mz) {
    const int b = blockIdx.x, t = threadIdx.x;
    float mg = -INFINITY;
    for (int i = 0; i < NBLK; ++i) mg = fmaxf(mg, part_ml[(b * NBLK + i) * 2]);
    float Z = 0.f, cA = 0.f, cB = 0.f;
    for (int i = 0; i < NBLK; ++i) {
        const float mi = part_ml[(b * NBLK + i) * 2];
        const float li = part_ml[(b * NBLK + i) * 2 + 1];
        const float sc = (mi == -INFINITY) ? 0.f : exp2f((mi - mg) * L2E);
        Z += li * sc;
        cA += part_c[(size_t)(b * NBLK + i) * DD + t] * sc;
        cB += part_c[(size_t)(b * NBLK + i) * DD + t + 256] * sc;
    }
    const float invZ = 1.0f / Z;   // Z>0: every sentence has >=1 valid word
    c_final[b * DD + t] = cA * invZ;
    c_final[b * DD + t + 256] = cB * invZ;
    if (t == 0) { mz[b * 2] = mg; mz[b * 2 + 1] = invZ; }
}

// ---------------------------------------------------------------------------
// K5: finalize align_vectors IN PLACE over the raw-score region of d_out:
// valid -> exp(a - m_g)/Z + 1e-20 ; masked -> 1e-20 exactly.
// grid (NN/256, B)
// ---------------------------------------------------------------------------
__global__ __launch_bounds__(256) void k_align(const int* __restrict__ wl,
                                               const float* __restrict__ mz,
                                               float* __restrict__ av) {
    const int b = blockIdx.y;
    const int n = blockIdx.x * 256 + threadIdx.x;
    const int s = n >> 6, w = n & 63;
    const int len = wl[b * SS + s];
    float v = 1e-20f;
    if (w < len) {
        const float a = av[b * NN + n];
        v = exp2f((a - mz[b * 2]) * L2E) * mz[b * 2 + 1] + 1e-20f;
    }
    av[b * NN + n] = v;
}

// ---------------------------------------------------------------------------
// K6: attn_h[b,d] = tanh( sum_k concat(c,source)[b,k] * W_out[d,k] )
// grid (2, B): thread handles one output d = x*256 + t.
// ---------------------------------------------------------------------------
__global__ __launch_bounds__(256) void k_attnh(const float* __restrict__ c_final,
                                               const float* __restrict__ src,
                                               const float* __restrict__ Wout,
                                               float* __restrict__ out) {
    __shared__ float xs[2 * DD];
    const int b = blockIdx.y, t = threadIdx.x;
    ((float2*)xs)[t] = ((const float2*)(c_final + b * DD))[t];
    ((float2*)(xs + DD))[t] = ((const float2*)(src + b * DD))[t];
    __syncthreads();
    const int d = blockIdx.x * 256 + t;
    const float* row = Wout + (size_t)d * (2 * DD);
    float acc = 0.f;
    for (int k = 0; k < 2 * DD; k += 4) {
        float4 x = *(const float4*)(xs + k);
        float4 w = *(const float4*)(row + k);
        acc += x.x * w.x + x.y * w.y + x.z * w.z + x.w * w.w;
    }
    out[b * DD + d] = tanhf(acc);
}

// ---------------------------------------------------------------------------
extern "C" void kernel_launch(void* const* d_in, const int* in_sizes, int n_in,
                              void* d_out, int out_size, void* d_ws, size_t ws_size,
                              hipStream_t stream) {
    const float* src = (const float*)d_in[0];   // [B, D]
    const float* wb  = (const float*)d_in[1];   // [WML, B, S, D]
    const int*   wl  = (const int*)  d_in[2];   // [B, S]
    const float* sb  = (const float*)d_in[3];   // [S, B, D]
    /* d_in[4] = sent_lengths: unused by forward math */
    const float* sa  = (const float*)d_in[5];   // [B, S]
    const float* Ww  = (const float*)d_in[6];   // [D, D]
    const float* Wsn = (const float*)d_in[7];   // [D, D]
    const float* Wo  = (const float*)d_in[8];   // [D, 2D]
    float* out = (float*)d_out;                 // [B*D] attn_h, then [B*N] align

    float* ws = (float*)d_ws;
    float* qw      = ws;                        // 32768
    float* qs      = ws + 32768;                // 32768
    float* sstat   = ws + 65536;                // 2560
    float* part_c  = ws + 68096;                // 64*20*512 = 655360
    float* part_ml = ws + 723456;               // 64*20*2   = 2560
    float* mz      = ws + 726016;               // 128
    float* c_final = ws + 726144;               // 32768  (end: 758912 floats ~= 3.0 MB)

    float* scores = out + BB * DD;              // raw scores live in the align slot

    hipLaunchKernelGGL(k_proj,   dim3(2, BB),       dim3(256), 0, stream, src, Ww, Wsn, qw, qs);
    hipLaunchKernelGGL(k_sstat,  dim3(BB),          dim3(256), 0, stream, qs, sb, sa, sstat);
    hipLaunchKernelGGL(k_main,   dim3(NBLK, BB),    dim3(256), 0, stream, wb, qw, sstat, wl,
                       scores, part_c, part_ml);
    hipLaunchKernelGGL(k_reduce, dim3(BB),          dim3(256), 0, stream, part_c, part_ml, c_final, mz);
    hipLaunchKernelGGL(k_align,  dim3(NN / 256, BB), dim3(256), 0, stream, wl, mz, scores);
    hipLaunchKernelGGL(k_attnh,  dim3(2, BB),       dim3(256), 0, stream, c_final, src, Wo, out);
}